// Round 2
// baseline (467.152 us; speedup 1.0000x reference)
//
#include <hip/hip_runtime.h>
#include <stdint.h>

// Fused attention: S=(x1@x2^T)*0.2; P=softmax(S); P=mask?P/0.9:0; O=P@x3
// B=16, SQ=SK=2048, D=DV=128. fp32 in/out, int32 mask, bf16 MFMA compute.
//
// R5 redesign vs R4 (181us; MfmaUtil 7.5%, VALU 13.8%, Occ 20% => latency-bound):
//  1. Pre-pass kernels convert K -> bf16 with XOR bank-swizzle baked into the
//     GLOBAL layout (col ^ ((k&7)<<3)), and V -> per-tile transposed bf16 with
//     the same XOR family (k ^ ((dv&7)<<3)). Main kernel stages via
//     global_load_lds width=16 (linear LDS dest + pre-swizzled source).
//  2. BQ=32 tile, k-split across wave pairs (4 waves: qh=wave&1, kh=wave>>1),
//     grid 1024. LDS = 16K(K)+16K(V)+5K(P) = 38KB -> 4 blocks/CU = 16 waves
//     (was 8). No kf/vf staging regs (-64 VGPR), no in-loop cvt, no scalar
//     b16 V writes. Cross-wave O/l combine in epilogue (reuses Ks as f32).
//  3. All LDS reads 2-way-or-free via the XOR swizzles; Ps stride 40.
//  4. Mask regs ping-pong (mA/mB), prefetched one tile ahead, issued AFTER
//     the staging barrier so their HBM latency hides under compute.
//  Carried: static-max softmax p=exp(0.2*s-12), XCD-chunked block swizzle,
//  v_cvt_pk_bf16_f32 packing, setprio(1) around MFMA clusters.
//  Fallback (ws too small): R4 kernel verbatim.

#define B_   16
#define SQ_  2048
#define SK_  2048
#define D_   128
#define DV_  128
#define BK   64
#define NT   (SK_ / BK)   // 32 tiles

typedef short  s16x8 __attribute__((ext_vector_type(8)));   // MFMA A/B frag
typedef float  f32x4 __attribute__((ext_vector_type(4)));   // MFMA C/D frag
typedef unsigned int u32x4 __attribute__((ext_vector_type(4)));
typedef unsigned short u16;
typedef unsigned int   u32;

// f32 pair -> packed bf16x2, RNE, single instruction (no builtin on gfx950).
__device__ __forceinline__ u32 pk2(float a, float b) {
    u32 r;
    asm("v_cvt_pk_bf16_f32 %0, %1, %2" : "=v"(r) : "v"(a), "v"(b));
    return r;
}
__device__ __forceinline__ u16 f2bf(float f) { return (u16)pk2(f, 0.0f); }

// async global->LDS, 16B per lane. dst = wave-uniform base (HW adds lane*16),
// src = per-lane address (pre-swizzled-global pattern).
__device__ __forceinline__ void gload16(u16* lds, const u16* g) {
    __builtin_amdgcn_global_load_lds((const __attribute__((address_space(1))) u32*)g,
                                     (__attribute__((address_space(3))) u32*)lds,
                                     16, 0, 0);
}

// ---------------- pre-pass: K -> bf16, bank-swizzled ----------------
// Kz[b][k][c] with c = col ^ ((k&7)<<3). 8 MB.
__global__ __launch_bounds__(256)
void prep_k(const float* __restrict__ Kg, u16* __restrict__ Kz)
{
    int g   = blockIdx.x * 256 + threadIdx.x;   // 524288 = 16*2048*16 groups
    int b   = g >> 15;
    int rem = g & 32767;
    int k   = rem >> 4;
    int grp = rem & 15;
    const float* src = Kg + ((size_t)b * SK_ + k) * D_ + grp * 8;
    float4 x = *(const float4*)(src);
    float4 y = *(const float4*)(src + 4);
    u32x4 w = { pk2(x.x, x.y), pk2(x.z, x.w), pk2(y.x, y.y), pk2(y.z, y.w) };
    int c = (grp * 8) ^ ((k & 7) << 3);
    *(u32x4*)(&Kz[((size_t)b * SK_ + k) * D_ + c]) = w;
}

// ---------------- pre-pass: V -> transposed bf16 tiles, swizzled ----------------
// Vz[b][kt][dv][c] with c = k_local ^ ((dv&7)<<3); tile = 128x64 bf16 = 16KB. 8 MB.
__global__ __launch_bounds__(256)
void prep_v(const float* __restrict__ Vg, u16* __restrict__ Vz)
{
    int g  = blockIdx.x * 256 + threadIdx.x;    // 524288 = 16*32*128*8 tasks
    int kg = g & 7;
    int dv = (g >> 3) & 127;
    int kt = (g >> 10) & 31;
    int b  = g >> 15;
    const float* src = Vg + ((size_t)b * SK_ + kt * 64 + kg * 8) * DV_ + dv;
    float v[8];
    #pragma unroll
    for (int jj = 0; jj < 8; ++jj) v[jj] = src[(size_t)jj * DV_];
    u32x4 w = { pk2(v[0], v[1]), pk2(v[2], v[3]), pk2(v[4], v[5]), pk2(v[6], v[7]) };
    int c = (kg * 8) ^ ((dv & 7) << 3);
    *(u32x4*)(&Vz[(((size_t)b * 32 + kt) * 128 + dv) * 64 + c]) = w;
}

// ---------------- main kernel ----------------
// One iteration body; MC = current-tile mask regs, MN = next-tile (prefetched).
#define BODY(IT, MC, MN)                                                      \
  {                                                                           \
    __syncthreads();   /* everyone done with previous tile's LDS */           \
    {                                                                         \
      const u16* Kt = Kz + kvbase + (size_t)(IT) * 8192;                      \
      const u16* Vt = Vz + kvbase + (size_t)(IT) * 8192;                      \
      _Pragma("unroll")                                                       \
      for (int i = 0; i < 4; ++i) {                                           \
        int c16 = (wave * 4 + i) * 512;                                       \
        gload16(&Ks[c16], &Kt[c16 + lane * 8]);                               \
        gload16(&Vs[c16], &Vt[c16 + lane * 8]);                               \
      }                                                                       \
    }                                                                         \
    __syncthreads();   /* staging complete + visible (drains vmcnt) */        \
    if ((IT) + 1 < NT) {                                                      \
      _Pragma("unroll")                                                       \
      for (int t = 0; t < 2; ++t)                                             \
        _Pragma("unroll")                                                     \
        for (int r = 0; r < 4; ++r)                                           \
          MN[t][r] = Mg[mbase + (size_t)r * SK_ + ((IT) + 1) * 64 + t * 16];  \
    }                                                                         \
    f32x4 s[2];                                                               \
    s[0] = (f32x4){0.f, 0.f, 0.f, 0.f};                                       \
    s[1] = (f32x4){0.f, 0.f, 0.f, 0.f};                                       \
    __builtin_amdgcn_s_setprio(1);                                            \
    _Pragma("unroll")                                                         \
    for (int kb = 0; kb < 4; ++kb) {                                          \
      _Pragma("unroll")                                                       \
      for (int t = 0; t < 2; ++t) {                                           \
        int kcol = kh * 32 + t * 16 + n16;                                    \
        int coff = (kb * 32 + quad * 8) ^ ((kcol & 7) << 3);                  \
        s16x8 bK = *(const s16x8*)(&Ks[kcol * 128 + coff]);                   \
        s[t] = __builtin_amdgcn_mfma_f32_16x16x32_bf16(aQ[kb], bK, s[t], 0, 0, 0); \
      }                                                                       \
    }                                                                         \
    __builtin_amdgcn_s_setprio(0);                                            \
    _Pragma("unroll")                                                         \
    for (int t = 0; t < 2; ++t)                                               \
      _Pragma("unroll")                                                       \
      for (int r = 0; r < 4; ++r) {                                           \
        float p = __expf(fmaf(s[t][r], 0.2f, -12.0f));                        \
        l_part[r] += p;                               /* UNmasked denom */    \
        float pv = MC[t][r] ? p : 0.f;                /* dropout */           \
        Ps[wave * 640 + (quad * 4 + r) * 40 + t * 16 + n16] = f2bf(pv);       \
      }                                                                       \
    s16x8 aP = *(const s16x8*)(&Ps[wave * 640 + n16 * 40 + quad * 8]);        \
    __builtin_amdgcn_s_setprio(1);                                            \
    _Pragma("unroll")                                                         \
    for (int nt = 0; nt < 8; ++nt) {                                          \
      int dv = nt * 16 + n16;                                                 \
      int coff = (kh * 32 + quad * 8) ^ ((dv & 7) << 3);                      \
      s16x8 bV = *(const s16x8*)(&Vs[dv * 64 + coff]);                        \
      o[nt] = __builtin_amdgcn_mfma_f32_16x16x32_bf16(aP, bV, o[nt], 0, 0, 0); \
    }                                                                         \
    __builtin_amdgcn_s_setprio(0);                                            \
  }

__global__ __launch_bounds__(256, 4)
void fattn_main(const float* __restrict__ Qg, const u16* __restrict__ Kz,
                const u16* __restrict__ Vz, const int* __restrict__ Mg,
                float* __restrict__ Og)
{
    __shared__ __align__(16) u16 Ks[64 * 128];     // 16384 B (epilogue: f32 oxch)
    __shared__ __align__(16) u16 Vs[128 * 64];     // 16384 B
    __shared__ __align__(16) u16 Ps[4 * 16 * 40];  //  5120 B (per-wave 16x32 chunks)
    __shared__ float lxch[32];
    // 38016 B -> 4 blocks/CU (16 waves)

    const int tid  = threadIdx.x;
    const int wave = tid >> 6;
    const int lane = tid & 63;
    const int n16  = lane & 15;
    const int quad = lane >> 4;
    const int qh   = wave & 1;    // q-half: rows qh*16..qh*16+15
    const int kh   = wave >> 1;   // k-half: cols kh*32..kh*32+31

    // XCD-chunked swizzle (bijective, 1024 % 8 == 0): XCD x owns batches
    // {2x,2x+1}; co-resident blocks (raw + 256m) share a batch -> K/V L2-hot.
    const int raw = blockIdx.x;
    const int xcd = raw & 7;
    const int j   = raw >> 3;            // 0..127
    const int b   = xcd * 2 + (j & 1);   // batch
    const int q0  = (j >> 1) << 5;       // q-tile origin (32 rows)

    // ---- Q fragments straight from global (one-time; no Qs LDS) ----
    s16x8 aQ[4];
    {
        const float* qsrc = Qg + ((size_t)b * SQ_ + q0 + qh * 16 + n16) * D_;
        #pragma unroll
        for (int kb = 0; kb < 4; ++kb) {
            float4 x = *(const float4*)(qsrc + kb * 32 + quad * 8);
            float4 y = *(const float4*)(qsrc + kb * 32 + quad * 8 + 4);
            u32x4 w = { pk2(x.x, x.y), pk2(x.z, x.w), pk2(y.x, y.y), pk2(y.z, y.w) };
            aQ[kb] = __builtin_bit_cast(s16x8, w);
        }
    }

    f32x4 o[8];
    #pragma unroll
    for (int i = 0; i < 8; ++i) o[i] = (f32x4){0.f, 0.f, 0.f, 0.f};
    float l_part[4] = {0.f, 0.f, 0.f, 0.f};   // partial exp-sums (this k-half)

    const size_t kvbase = (size_t)b * 262144;   // 512KB slab per batch (u16), K and V alike
    const size_t mbase  = ((size_t)b * SQ_ + q0 + qh * 16 + quad * 4) * (size_t)SK_
                        + kh * 32 + n16;

    int mA[2][4], mB[2][4];
    #pragma unroll
    for (int t = 0; t < 2; ++t)
        #pragma unroll
        for (int r = 0; r < 4; ++r)
            mA[t][r] = Mg[mbase + (size_t)r * SK_ + t * 16];

    for (int it = 0; it < NT; it += 2) {
        BODY(it,     mA, mB)
        BODY(it + 1, mB, mA)
    }

    // ---- epilogue: reduce l across n16 lanes; cross-wave combine k-halves ----
    float lr[4];
    #pragma unroll
    for (int r = 0; r < 4; ++r) {
        float l = l_part[r];
        #pragma unroll
        for (int off = 1; off < 16; off <<= 1) l += __shfl_xor(l, off);
        lr[r] = l;
    }
    __syncthreads();   // all compute done; Ks reusable as f32 exchange buffer
    float* oxch = (float*)Ks;   // 32 x 128 f32 = 16384 B, exact fit
    if (kh == 1) {
        #pragma unroll
        for (int r = 0; r < 4; ++r) {
            int row = qh * 16 + quad * 4 + r;
            #pragma unroll
            for (int nt = 0; nt < 8; ++nt)
                oxch[row * 128 + nt * 16 + n16] = o[nt][r];
            if (n16 == 0) lxch[row] = lr[r];
        }
    }
    __syncthreads();
    if (kh == 0) {
        const float ksc = 1.0f / 0.9f;
        #pragma unroll
        for (int r = 0; r < 4; ++r) {
            int row = qh * 16 + quad * 4 + r;
            float inv = ksc / (lr[r] + lxch[row]);
            size_t ob = ((size_t)b * SQ_ + q0 + row) * (size_t)DV_;
            #pragma unroll
            for (int nt = 0; nt < 8; ++nt)
                Og[ob + nt * 16 + n16] = (o[nt][r] + oxch[row * 128 + nt * 16 + n16]) * inv;
        }
    }
}

// ---------------- fallback (R4 kernel, used only if workspace too small) ----------------
#define BQ_FB 64
#define LDQ  136
#define LDK  136
#define LDVT 72
#define LDP  72

__global__ __launch_bounds__(256, 2)
void fattn_fb(const float* __restrict__ Qg, const float* __restrict__ Kg,
              const float* __restrict__ Vg, const int* __restrict__ Mg,
              float* __restrict__ Og)
{
    __shared__ u16 Qs[BQ_FB * LDQ];
    __shared__ u16 Ks[BK * LDK];
    __shared__ u16 Vt[DV_ * LDVT];
    __shared__ u16 Ps[4 * 16 * LDP];

    const int tid  = threadIdx.x;
    const int wave = tid >> 6;
    const int lane = tid & 63;
    const int n16  = lane & 15;
    const int quad = lane >> 4;

    const int raw = blockIdx.x;
    const int xcd = raw & 7;
    const int j   = raw >> 3;
    const int b   = xcd * 2 + (j & 1);
    const int q0  = (j >> 1) << 6;

    const int srow = tid >> 4;
    const int scol = (tid & 15) * 8;
    const int vrot = (tid & 7) * 8;

    {
        const float* src = Qg + ((size_t)b * SQ_ + q0) * D_;
        #pragma unroll
        for (int c = 0; c < 4; ++c) {
            int row = c * 16 + srow;
            float4 v0 = *(const float4*)(&src[row * D_ + scol]);
            float4 v1 = *(const float4*)(&src[row * D_ + scol + 4]);
            uint4 pk = { pk2(v0.x, v0.y), pk2(v0.z, v0.w),
                         pk2(v1.x, v1.y), pk2(v1.z, v1.w) };
            *(uint4*)(&Qs[row * LDQ + scol]) = pk;
        }
    }
    __syncthreads();

    s16x8 aQ[4];
    {
        const int qr = wave * 16 + n16;
        #pragma unroll
        for (int kb = 0; kb < 4; ++kb)
            aQ[kb] = *(const s16x8*)(&Qs[qr * LDQ + kb * 32 + quad * 8]);
    }

    f32x4 o[8];
    #pragma unroll
    for (int i = 0; i < 8; ++i) o[i] = (f32x4){0.f, 0.f, 0.f, 0.f};
    float l_part[4] = {0.f, 0.f, 0.f, 0.f};

    const size_t mask_qbase = ((size_t)b * SQ_ + q0 + wave * 16 + quad * 4) * (size_t)SK_;
    const float* baseK = Kg + ((size_t)b * SK_) * D_;
    const float* baseV = Vg + ((size_t)b * SK_) * DV_;

    float4 kf[8], vf[8];
    #pragma unroll
    for (int c = 0; c < 4; ++c) {
        int row = c * 16 + srow;
        kf[2*c]   = *(const float4*)(&baseK[row * D_ + scol]);
        kf[2*c+1] = *(const float4*)(&baseK[row * D_ + scol + 4]);
        vf[2*c]   = *(const float4*)(&baseV[row * DV_ + scol]);
        vf[2*c+1] = *(const float4*)(&baseV[row * DV_ + scol + 4]);
    }
    int mkc[4][4], mkn[4][4];
    #pragma unroll
    for (int t = 0; t < 4; ++t)
        #pragma unroll
        for (int r = 0; r < 4; ++r)
            mkc[t][r] = Mg[mask_qbase + (size_t)r * SK_ + (t * 16 + n16)];

    for (int it = 0; it < NT; ++it) {
        __syncthreads();
        #pragma unroll
        for (int c = 0; c < 4; ++c) {
            int row = c * 16 + srow;
            uint4 pk = { pk2(kf[2*c].x, kf[2*c].y),     pk2(kf[2*c].z, kf[2*c].w),
                         pk2(kf[2*c+1].x, kf[2*c+1].y), pk2(kf[2*c+1].z, kf[2*c+1].w) };
            *(uint4*)(&Ks[row * LDK + scol]) = pk;
        }
        #pragma unroll
        for (int c = 0; c < 4; ++c) {
            int k    = c * 16 + srow;
            int rcol = (k + vrot) & 63;
            int dv0  = scol;
            u32 r0 = pk2(vf[2*c].x,   vf[2*c].y);
            u32 r1 = pk2(vf[2*c].z,   vf[2*c].w);
            u32 r2 = pk2(vf[2*c+1].x, vf[2*c+1].y);
            u32 r3 = pk2(vf[2*c+1].z, vf[2*c+1].w);
            Vt[(dv0 + 0) * LDVT + rcol] = (u16)r0;
            Vt[(dv0 + 1) * LDVT + rcol] = (u16)(r0 >> 16);
            Vt[(dv0 + 2) * LDVT + rcol] = (u16)r1;
            Vt[(dv0 + 3) * LDVT + rcol] = (u16)(r1 >> 16);
            Vt[(dv0 + 4) * LDVT + rcol] = (u16)r2;
            Vt[(dv0 + 5) * LDVT + rcol] = (u16)(r2 >> 16);
            Vt[(dv0 + 6) * LDVT + rcol] = (u16)r3;
            Vt[(dv0 + 7) * LDVT + rcol] = (u16)(r3 >> 16);
        }
        if (it + 1 < NT) {
            const int k0n = (it + 1) * BK;
            #pragma unroll
            for (int c = 0; c < 4; ++c) {
                int row = k0n + c * 16 + srow;
                kf[2*c]   = *(const float4*)(&baseK[row * D_ + scol]);
                kf[2*c+1] = *(const float4*)(&baseK[row * D_ + scol + 4]);
                vf[2*c]   = *(const float4*)(&baseV[row * DV_ + scol]);
                vf[2*c+1] = *(const float4*)(&baseV[row * DV_ + scol + 4]);
            }
            #pragma unroll
            for (int t = 0; t < 4; ++t)
                #pragma unroll
                for (int r = 0; r < 4; ++r)
                    mkn[t][r] = Mg[mask_qbase + (size_t)r * SK_ + (k0n + t * 16 + n16)];
        }
        __syncthreads();

        f32x4 s[4];
        #pragma unroll
        for (int t = 0; t < 4; ++t) s[t] = (f32x4){0.f, 0.f, 0.f, 0.f};
        #pragma unroll
        for (int kb = 0; kb < 4; ++kb) {
            #pragma unroll
            for (int t = 0; t < 4; ++t) {
                s16x8 bK = *(const s16x8*)(&Ks[(t * 16 + n16) * LDK + kb * 32 + quad * 8]);
                s[t] = __builtin_amdgcn_mfma_f32_16x16x32_bf16(aQ[kb], bK, s[t], 0, 0, 0);
            }
        }
        #pragma unroll
        for (int t = 0; t < 4; ++t)
            #pragma unroll
            for (int r = 0; r < 4; ++r) {
                float p = __expf(fmaf(s[t][r], 0.2f, -12.0f));
                l_part[r] += p;
                float pv = mkc[t][r] ? p : 0.f;
                Ps[(wave * 16 + quad * 4 + r) * LDP + t * 16 + n16] = f2bf(pv);
            }
        #pragma unroll
        for (int kk = 0; kk < 2; ++kk) {
            s16x8 aP = *(const s16x8*)(&Ps[(wave * 16 + n16) * LDP + kk * 32 + quad * 8]);
            #pragma unroll
            for (int nt = 0; nt < 8; ++nt) {
                int dv   = nt * 16 + n16;
                int rcol = (kk * 32 + quad * 8 + 8 * ((dv >> 3) & 7)) & 63;
                s16x8 bV = *(const s16x8*)(&Vt[dv * LDVT + rcol]);
                o[nt] = __builtin_amdgcn_mfma_f32_16x16x32_bf16(aP, bV, o[nt], 0, 0, 0);
            }
        }
        #pragma unroll
        for (int t = 0; t < 4; ++t)
            #pragma unroll
            for (int r = 0; r < 4; ++r) mkc[t][r] = mkn[t][r];
    }

    const float keep_scale = 1.0f / 0.9f;
    #pragma unroll
    for (int r = 0; r < 4; ++r) {
        float l = l_part[r];
        #pragma unroll
        for (int off = 1; off < 16; off <<= 1)
            l += __shfl_xor(l, off);
        float inv_l = keep_scale / l;
        size_t obase = ((size_t)b * SQ_ + q0 + wave * 16 + quad * 4 + r) * DV_;
        #pragma unroll
        for (int nt = 0; nt < 8; ++nt)
            Og[obase + nt * 16 + n16] = o[nt][r] * inv_l;
    }
}

extern "C" void kernel_launch(void* const* d_in, const int* in_sizes, int n_in,
                              void* d_out, int out_size, void* d_ws, size_t ws_size,
                              hipStream_t stream) {
    const float* Qg = (const float*)d_in[0];
    const float* Kg = (const float*)d_in[1];
    const float* Vg = (const float*)d_in[2];
    const int*   Mg = (const int*)d_in[3];
    float* Og = (float*)d_out;
    if (d_ws != nullptr && ws_size >= (size_t)16 * 1024 * 1024) {
        u16* Kz = (u16*)d_ws;          // 8 MB swizzled bf16 K
        u16* Vz = Kz + 4194304;        // 8 MB transposed+swizzled bf16 V
        prep_k<<<dim3(2048), 256, 0, stream>>>(Kg, Kz);
        prep_v<<<dim3(2048), 256, 0, stream>>>(Vg, Vz);
        fattn_main<<<dim3(1024), 256, 0, stream>>>(Qg, Kz, Vz, Mg, Og);
    } else {
        fattn_fb<<<dim3(512), 256, 0, stream>>>(Qg, Kg, Vg, Mg, Og);
    }
}